// Round 1
// baseline (451.911 us; speedup 1.0000x reference)
//
#include <hip/hip_runtime.h>
#include <math.h>

// ---------- types / helpers ----------
typedef __attribute__((ext_vector_type(8))) short short8;   // 8 bf16 (4 VGPRs)
typedef __attribute__((ext_vector_type(4))) float f32x4;    // MFMA acc

#define MFMA16(a, b, c) __builtin_amdgcn_mfma_f32_16x16x32_bf16((a), (b), (c), 0, 0, 0)

// async global->LDS, 16B per lane. LDS dest is wave-uniform base + lane*16;
// the GLOBAL source address is per-lane -> swizzle the source for free.
__device__ inline void gl_lds16(const void* g, void* l) {
  __builtin_amdgcn_global_load_lds(
      (const __attribute__((address_space(1))) void*)g,
      (__attribute__((address_space(3))) void*)l, 16, 0, 0);
}

__device__ inline unsigned int pack2(float lo, float hi) {
  unsigned int ulo = __float_as_uint(lo), uhi = __float_as_uint(hi);
  return (uhi & 0xFFFF0000u) | (ulo >> 16);
}
__device__ inline unsigned short f2bf_r(float f) {
  return (unsigned short)((__float_as_uint(f) + 0x8000u) >> 16);
}
__device__ inline float bf2f(unsigned short h) {
  return __uint_as_float(((unsigned int)h) << 16);
}

// ---------- K0: merged weight repack ----------
// blocks 0..95:   W1 [3,2048,128] f32 -> W1bt [384,2048] bf16 (B^T, k-contiguous)
// blocks 96..287: W2 [3,128,128] f32  -> W2t  [j][d][c]  bf16 (transposed)
__global__ __launch_bounds__(256) void k_repack(const float* __restrict__ W1,
                                                const float* __restrict__ W2,
                                                unsigned short* __restrict__ W1bt,
                                                unsigned short* __restrict__ W2t) {
  __shared__ float tile[64 * 128];   // 32 KB
  const int b = blockIdx.x, tid = threadIdx.x;
  if (b < 96) {
    const int k = b >> 5, et = b & 31;
    const int e0 = et * 64;
    const float* src = W1 + (size_t)k * 262144 + (size_t)e0 * 128;
#pragma unroll
    for (int i = 0; i < 8; ++i) {
      int idx4 = tid + i * 256;
      ((f32x4*)tile)[idx4] = ((const f32x4*)src)[idx4];
    }
    __syncthreads();
#pragma unroll
    for (int i = 0; i < 4; ++i) {
      int item = tid + i * 256;
      int c = item >> 3, eo = (item & 7) * 8;
      union { unsigned short h[8]; uint4 v; } t;
#pragma unroll
      for (int u = 0; u < 8; ++u) t.h[u] = f2bf_r(tile[(eo + u) * 128 + c]);
      *(uint4*)(W1bt + (size_t)(k * 128 + c) * 2048 + e0 + eo) = t.v;
    }
  } else {
    int idx = (b - 96) * 256 + tid;                 // 49152
    int j = idx >> 14, r = idx & 16383, d = r >> 7, c = r & 127;
    W2t[idx] = f2bf_r(W2[(size_t)j * 16384 + (size_t)c * 128 + d]);
  }
}

// ---------- K1: fused stage1 GEMM + tap-sum/tanh + stage2 GEMM + log-softmax ----------
// 512 blocks x 64 out rows. Stage-1 computes rows r0-4..r0+63 (68 staged, 80 logical).
// Main loop: double-buffered LDS (2 x 66560 B), prefetch chunk t+1 BEFORE computing
// chunk t, single __syncthreads() per chunk (its vmcnt(0)+barrier covers both the
// prefetch drain and the LDS-read completion). 1 block/CU (LDS 130 KB).
__global__ __launch_bounds__(256, 1) void k_fused(const float* __restrict__ X,
                                                  const unsigned short* __restrict__ Bt,
                                                  const unsigned short* __restrict__ W2t,
                                                  const float* __restrict__ b1,
                                                  const float* __restrict__ b2,
                                                  float* __restrict__ out) {
  // dbuf: buffer p at smem + p*66560; within buffer: A f32 17408 B, then B bf16 49152 B
  __shared__ __align__(16) char smem[133120];
  unsigned short* Yt = (unsigned short*)smem;             // phase B: 80 x 392 bf16 (62,720 B)
  float* zbuf = (float*)(smem + 62720);                   // 2 x 128 f32

  const int r0 = blockIdx.x * 64;
  const int tid = threadIdx.x, wave = tid >> 6, lane = tid & 63;
  const int mrow = lane & 15, quad = lane >> 4;

  // ---- stage-1 staging pointers: A-buf row i <-> X row r0-4+i (clamped) ----
  const float* agp[5];
#pragma unroll
  for (int r = 0; r < 4; ++r) {
    int i = wave * 16 + r * 4 + (lane >> 4);
    int g = r0 - 4 + i; if (g < 0) g = 0;             // block 0 halo clamp (masked later)
    int c = (lane & 15) ^ (i & 15);
    agp[r] = X + (size_t)g * 2048 + c * 4;
  }
  {
    int i = 64 + (lane >> 4);                         // wave-0 extra: rows 64..67
    int c = (lane & 15) ^ (i & 15);
    agp[4] = X + (size_t)(r0 - 4 + i) * 2048 + c * 4;
  }
  const unsigned short* bgp[12];
#pragma unroll
  for (int r = 0; r < 12; ++r) {
    int col = wave * 96 + r * 8 + (lane >> 3);
    int c = (lane & 7) ^ (col & 7);
    bgp[r] = Bt + (size_t)col * 2048 + c * 8;
  }

  f32x4 acc[5][6] = {};   // wave: 80 logical rows (5 rt) x 96 cols (6 ct)

  // issue all 17 A-stages + 12 B-stages for the next chunk, then advance pointers
  auto stage = [&](char* base) {
    char* An = base;
    char* Bn = base + 17408;
#pragma unroll
    for (int r = 0; r < 4; ++r)
      gl_lds16(agp[r], An + (wave * 16 + r * 4) * 256);
    if (wave == 0) gl_lds16(agp[4], An + 64 * 256);
#pragma unroll
    for (int r = 0; r < 12; ++r)
      gl_lds16(bgp[r], Bn + (wave * 96 + r * 8) * 128);
#pragma unroll
    for (int r = 0; r < 5; ++r) agp[r] += 64;
#pragma unroll
    for (int r = 0; r < 12; ++r) bgp[r] += 64;
  };

  // prologue: fill buffer 0 with chunk 0
  stage(smem);
  __syncthreads();

#pragma unroll 2
  for (int t = 0; t < 32; ++t) {
    const int cur = t & 1;
    // prefetch chunk t+1 into the other buffer; loads stay in flight under compute
    if (t < 31) stage(smem + (cur ^ 1) * 66560);

    const float* Af = (const float*)(smem + cur * 66560);
    const unsigned short* Bh = (const unsigned short*)(smem + cur * 66560 + 17408);
#pragma unroll
    for (int s = 0; s < 2; ++s) {
      short8 af[5];
#pragma unroll
      for (int rt = 0; rt < 5; ++rt) {                // rt=4 rows 68..79 read garbage (unused)
        int row = rt * 16 + mrow;
        int c0 = s * 8 + quad * 2;
        const float* base = Af + row * 64;
        f32x4 x0 = *(const f32x4*)(base + ((c0 ^ mrow) * 4));
        f32x4 x1 = *(const f32x4*)(base + (((c0 + 1) ^ mrow) * 4));
        union { unsigned int u[4]; short8 v; } tt;
        tt.u[0] = pack2(x0[0], x0[1]); tt.u[1] = pack2(x0[2], x0[3]);
        tt.u[2] = pack2(x1[0], x1[1]); tt.u[3] = pack2(x1[2], x1[3]);
        af[rt] = tt.v;
      }
#pragma unroll
      for (int ct = 0; ct < 6; ++ct) {
        int col = wave * 96 + ct * 16 + mrow;
        int ch = (s * 4 + quad) ^ (mrow & 7);
        short8 bf = *(const short8*)(Bh + col * 64 + ch * 8);
#pragma unroll
        for (int rt = 0; rt < 5; ++rt)
          acc[rt][ct] = MFMA16(af[rt], bf, acc[rt][ct]);
      }
    }
    // one barrier per chunk: drains this chunk's LDS reads AND the prefetch vmcnt
    __syncthreads();
  }

  // ---- spill acc -> Yt (bf16). Yt row i <-> Y global row r0-4+i; stride 392 (4-bank shift) ----
#pragma unroll
  for (int rt = 0; rt < 5; ++rt)
#pragma unroll
    for (int ct = 0; ct < 6; ++ct)
#pragma unroll
      for (int rg = 0; rg < 4; ++rg) {
        int l = rt * 16 + quad * 4 + rg;
        int col = wave * 96 + ct * 16 + mrow;
        Yt[l * 392 + col] = f2bf_r(acc[rt][ct][rg]);
      }
  __syncthreads();

  // ---- H[p]=tanh(sum taps + cnt*b1), p in [r0-2, r0+63]; store in-place at dead tap-2 slot ----
  // H[p] slot = Yt[p-r0+2][256+c]. Self-RMW per element: race-free (blk0/blk1 never written).
  for (int idx = tid; idx < 66 * 128; idx += 256) {
    int hl = idx >> 7, c = idx & 127;
    int p = r0 - 2 + hl;
    int i = hl + 2;                                   // tap-0 Yt row
    float h = 0.f;
    if (p >= 0) {
      float s = bf2f(Yt[i * 392 + c]);
      float cnt = 1.f;
      if (p >= 1) { s += bf2f(Yt[(i - 1) * 392 + 128 + c]); cnt += 1.f; }
      if (p >= 2) { s += bf2f(Yt[(i - 2) * 392 + 256 + c]); cnt += 1.f; }
      h = tanhf(fmaf(cnt, b1[c], s));
    }
    Yt[(i - 2) * 392 + 256 + c] = f2bf_r(h);          // = Yt[hl][256+c], holds H[r0-2+hl]
  }
  __syncthreads();

  // ---- stage-2: Z rows r0+wave*16..+15; A-frag H row = Yt[wave*16+mrow+j][256+...] ----
  f32x4 acc2[8] = {};
#pragma unroll
  for (int j = 0; j < 3; ++j) {
#pragma unroll
    for (int kk = 0; kk < 4; ++kk) {
      short8 a0 = *(const short8*)&Yt[(wave * 16 + mrow + j) * 392 + 256 + kk * 32 + quad * 8];
      const unsigned short* wp = W2t + (size_t)(j * 128 + mrow) * 128 + kk * 32 + quad * 8;
#pragma unroll
      for (int ct = 0; ct < 8; ++ct)
        acc2[ct] = MFMA16(a0, *(const short8*)(wp + ct * 16 * 128), acc2[ct]);
    }
  }

  // ---- log-softmax per row (128 cols = 16 lanes x 8 ct-regs) ----
#pragma unroll
  for (int rg = 0; rg < 4; ++rg) {
    float z[8]; float m = -1e30f;
#pragma unroll
    for (int ct = 0; ct < 8; ++ct) {
      z[ct] = acc2[ct][rg] + 3.f * b2[ct * 16 + mrow];
      m = fmaxf(m, z[ct]);
    }
#pragma unroll
    for (int off = 1; off < 16; off <<= 1) m = fmaxf(m, __shfl_xor(m, off, 64));
    float s = 0.f;
#pragma unroll
    for (int ct = 0; ct < 8; ++ct) s += __expf(z[ct] - m);
#pragma unroll
    for (int off = 1; off < 16; off <<= 1) s += __shfl_xor(s, off, 64);
    float lse = m + __logf(s);
    int grow = r0 + wave * 16 + quad * 4 + rg;
    if (grow >= 2) {
      float* op = out + (size_t)grow * 128 + mrow;
#pragma unroll
      for (int ct = 0; ct < 8; ++ct) op[ct * 16] = z[ct] - lse;
    }
  }

  // ---- fallback rows 0,1 (block 0): Z0 = tanh(Y[row][0:128]+b1) @ W2[0] + b2 ----
  if (blockIdx.x == 0) {
    __syncthreads();
    int row = tid >> 7, d = tid & 127;
    zbuf[row * 128 + d] = tanhf(bf2f(Yt[(row + 4) * 392 + d]) + b1[d]);  // blk0 cols intact
    __syncthreads();
    float zv = b2[d];
    for (int c = 0; c < 128; ++c)
      zv = fmaf(zbuf[row * 128 + c], bf2f(W2t[(size_t)d * 128 + c]), zv); // W2t[0][d][c]=W2[0][c][d]
    __syncthreads();
    zbuf[row * 128 + d] = zv;
    __syncthreads();
    float m = -1e30f;
    for (int c = 0; c < 128; ++c) m = fmaxf(m, zbuf[row * 128 + c]);
    float s = 0.f;
    for (int c = 0; c < 128; ++c) s += __expf(zbuf[row * 128 + c] - m);
    out[(size_t)row * 128 + d] = zv - m - __logf(s);
  }
}

// ---------- launch ----------
extern "C" void kernel_launch(void* const* d_in, const int* in_sizes, int n_in,
                              void* d_out, int out_size, void* d_ws, size_t ws_size,
                              hipStream_t stream) {
  const float* X  = (const float*)d_in[0];   // [32768, 1, 2048]
  const float* W1 = (const float*)d_in[1];   // [3, 2048, 128]
  const float* b1 = (const float*)d_in[2];   // [1, 128]
  const float* W2 = (const float*)d_in[3];   // [3, 128, 128]
  const float* b2 = (const float*)d_in[4];   // [1, 128]
  float* out = (float*)d_out;                // [32768, 1, 128] fp32

  unsigned short* W1bt = (unsigned short*)d_ws;                    // 384*2048*2 = 1,572,864
  unsigned short* W2t  = (unsigned short*)((char*)d_ws + 1572864); // 98,304

  k_repack<<<288, 256, 0, stream>>>(W1, W2, W1bt, W2t);
  k_fused<<<512, 256, 0, stream>>>(X, W1bt, W2t, b1, b2, out);
}

// Round 2
// 441.841 us; speedup vs baseline: 1.0228x; 1.0228x over previous
//
#include <hip/hip_runtime.h>
#include <math.h>

// ---------- types / helpers ----------
typedef __attribute__((ext_vector_type(8))) short short8;   // 8 bf16 (4 VGPRs)
typedef __attribute__((ext_vector_type(4))) float f32x4;    // MFMA acc

#define MFMA16(a, b, c) __builtin_amdgcn_mfma_f32_16x16x32_bf16((a), (b), (c), 0, 0, 0)

// async global->LDS, 16B per lane. LDS dest is wave-uniform base + lane*16;
// the GLOBAL source address is per-lane -> swizzle the source for free.
__device__ inline void gl_lds16(const void* g, void* l) {
  __builtin_amdgcn_global_load_lds(
      (const __attribute__((address_space(1))) void*)g,
      (__attribute__((address_space(3))) void*)l, 16, 0, 0);
}

__device__ inline unsigned int pack2(float lo, float hi) {
  unsigned int ulo = __float_as_uint(lo), uhi = __float_as_uint(hi);
  return (uhi & 0xFFFF0000u) | (ulo >> 16);
}
__device__ inline unsigned short f2bf_r(float f) {
  return (unsigned short)((__float_as_uint(f) + 0x8000u) >> 16);
}
__device__ inline float bf2f(unsigned short h) {
  return __uint_as_float(((unsigned int)h) << 16);
}

// ---------- K0: merged weight repack ----------
// blocks 0..95:   W1 [3,2048,128] f32 -> W1bt [384,2048] bf16 (B^T, k-contiguous)
// blocks 96..287: W2 [3,128,128] f32  -> W2t  [j][d][c]  bf16 (transposed)
__global__ __launch_bounds__(256) void k_repack(const float* __restrict__ W1,
                                                const float* __restrict__ W2,
                                                unsigned short* __restrict__ W1bt,
                                                unsigned short* __restrict__ W2t) {
  __shared__ float tile[64 * 128];   // 32 KB
  const int b = blockIdx.x, tid = threadIdx.x;
  if (b < 96) {
    const int k = b >> 5, et = b & 31;
    const int e0 = et * 64;
    const float* src = W1 + (size_t)k * 262144 + (size_t)e0 * 128;
#pragma unroll
    for (int i = 0; i < 8; ++i) {
      int idx4 = tid + i * 256;
      ((f32x4*)tile)[idx4] = ((const f32x4*)src)[idx4];
    }
    __syncthreads();
#pragma unroll
    for (int i = 0; i < 4; ++i) {
      int item = tid + i * 256;
      int c = item >> 3, eo = (item & 7) * 8;
      union { unsigned short h[8]; uint4 v; } t;
#pragma unroll
      for (int u = 0; u < 8; ++u) t.h[u] = f2bf_r(tile[(eo + u) * 128 + c]);
      *(uint4*)(W1bt + (size_t)(k * 128 + c) * 2048 + e0 + eo) = t.v;
    }
  } else {
    int idx = (b - 96) * 256 + tid;                 // 49152
    int j = idx >> 14, r = idx & 16383, d = r >> 7, c = r & 127;
    W2t[idx] = f2bf_r(W2[(size_t)j * 16384 + (size_t)c * 128 + d]);
  }
}

// ---------- K1: fused stage1 GEMM + tap-sum/tanh + stage2 GEMM + log-softmax ----------
// 512 blocks x 64 out rows. Stage-1 computes rows r0-4..r0+63 (72 staged, 80 logical).
// BK=32, double-buffered LDS (2 x 33792 B = 67584 B total -> 2 blocks/CU), prefetch
// chunk t+1 BEFORE computing chunk t, one __syncthreads() per chunk. This keeps BOTH
// the block-level overlap (2 resident blocks) and intra-block load/compute overlap.
__global__ __launch_bounds__(256, 2) void k_fused(const float* __restrict__ X,
                                                  const unsigned short* __restrict__ Bt,
                                                  const unsigned short* __restrict__ W2t,
                                                  const float* __restrict__ b1,
                                                  const float* __restrict__ b2,
                                                  float* __restrict__ out) {
  // buffer p at smem + p*33792: A f32 72 rows x 128 B (9216 B), chunk c at slot c^(row&7)
  //                             B bf16 384 cols x 64 B (24576 B), chunk c at slot c^(col&3)
  __shared__ __align__(16) char smem[67584];
  unsigned short* Yt = (unsigned short*)smem;             // phase B: 80 x 392 bf16 (62,720 B)
  float* zbuf = (float*)(smem + 62720);                   // 2 x 128 f32

  const int r0 = blockIdx.x * 64;
  const int tid = threadIdx.x, wave = tid >> 6, lane = tid & 63;
  const int mrow = lane & 15, quad = lane >> 4;

  // ---- A staging: 9 wave-loads (72 rows, 8 rows/load). wave w: loads {w, w+4}; wave0 also 8.
  // A-buf row i <-> X row r0-4+i (clamped both ends; clamped rows are masked/unused later).
  const float* agp[3];
  {
    const int aj[3] = { wave, wave + 4, 8 };
#pragma unroll
    for (int jj = 0; jj < 3; ++jj) {
      int j = aj[jj];
      int g = r0 - 4 + j * 8 + (lane >> 3);
      if (g < 0) g = 0;
      if (g > 32767) g = 32767;
      int c = (lane & 7) ^ (lane >> 3);                 // row&7 == lane>>3 (8 rows/load)
      agp[jj] = X + (size_t)g * 2048 + c * 4;
    }
  }
  // ---- B staging: 24 wave-loads (16 cols/load). wave w: loads w*6..w*6+5 (cols w*96+jj*16..)
  const unsigned short* bgp[6];
#pragma unroll
  for (int jj = 0; jj < 6; ++jj) {
    int col = wave * 96 + jj * 16 + (lane >> 2);
    int c = (lane & 3) ^ ((lane >> 2) & 3);             // col&3 == (lane>>2)&3
    bgp[jj] = Bt + (size_t)col * 2048 + c * 8;
  }

  f32x4 acc[5][6] = {};   // wave: 80 logical rows (5 rt) x 96 cols (6 ct)

  auto stage = [&](char* base) {
    char* An = base;
    char* Bn = base + 9216;
    gl_lds16(agp[0], An + wave * 1024);
    gl_lds16(agp[1], An + (wave + 4) * 1024);
    if (wave == 0) gl_lds16(agp[2], An + 8 * 1024);
#pragma unroll
    for (int jj = 0; jj < 6; ++jj)
      gl_lds16(bgp[jj], Bn + (wave * 6 + jj) * 1024);
#pragma unroll
    for (int jj = 0; jj < 3; ++jj) agp[jj] += 32;       // next K-chunk (32 floats)
#pragma unroll
    for (int jj = 0; jj < 6; ++jj) bgp[jj] += 32;       // next K-chunk (32 bf16)
  };

  // prologue: fill buffer 0 with chunk 0
  stage(smem);
  __syncthreads();

#pragma unroll 2
  for (int t = 0; t < 64; ++t) {
    const int cur = t & 1;
    // prefetch chunk t+1 into the other buffer; loads stay in flight under compute
    if (t < 63) stage(smem + (cur ^ 1) * 33792);

    const float* Af = (const float*)(smem + cur * 33792);
    const unsigned short* Bh = (const unsigned short*)(smem + cur * 33792 + 9216);

    short8 af[5];
#pragma unroll
    for (int rt = 0; rt < 5; ++rt) {                    // rt=4 rows 72..79 read garbage (unused)
      int row = rt * 16 + mrow;
      int c0 = quad * 2;
      const float* base = Af + row * 32;
      f32x4 x0 = *(const f32x4*)(base + ((c0 ^ (mrow & 7)) * 4));
      f32x4 x1 = *(const f32x4*)(base + (((c0 + 1) ^ (mrow & 7)) * 4));
      union { unsigned int u[4]; short8 v; } tt;
      tt.u[0] = pack2(x0[0], x0[1]); tt.u[1] = pack2(x0[2], x0[3]);
      tt.u[2] = pack2(x1[0], x1[1]); tt.u[3] = pack2(x1[2], x1[3]);
      af[rt] = tt.v;
    }
#pragma unroll
    for (int ct = 0; ct < 6; ++ct) {
      int col = wave * 96 + ct * 16 + mrow;
      int sl = quad ^ (mrow & 3);
      short8 bf = *(const short8*)(Bh + col * 32 + sl * 8);
#pragma unroll
      for (int rt = 0; rt < 5; ++rt)
        acc[rt][ct] = MFMA16(af[rt], bf, acc[rt][ct]);
    }
    // one barrier per chunk: drains this chunk's prefetch vmcnt (overlapped with the
    // compute above) and fences LDS reads before next iteration's stage overwrites cur^1
    __syncthreads();
  }

  // ---- spill acc -> Yt (bf16). Yt row i <-> Y global row r0-4+i; stride 392 (4-bank shift) ----
#pragma unroll
  for (int rt = 0; rt < 5; ++rt)
#pragma unroll
    for (int ct = 0; ct < 6; ++ct)
#pragma unroll
      for (int rg = 0; rg < 4; ++rg) {
        int l = rt * 16 + quad * 4 + rg;
        int col = wave * 96 + ct * 16 + mrow;
        Yt[l * 392 + col] = f2bf_r(acc[rt][ct][rg]);
      }
  __syncthreads();

  // ---- H[p]=tanh(sum taps + cnt*b1), p in [r0-2, r0+63]; store in-place at dead tap-2 slot ----
  // H[p] slot = Yt[p-r0+2][256+c]. Self-RMW per element: race-free (blk0/blk1 never written).
  for (int idx = tid; idx < 66 * 128; idx += 256) {
    int hl = idx >> 7, c = idx & 127;
    int p = r0 - 2 + hl;
    int i = hl + 2;                                   // tap-0 Yt row
    float h = 0.f;
    if (p >= 0) {
      float s = bf2f(Yt[i * 392 + c]);
      float cnt = 1.f;
      if (p >= 1) { s += bf2f(Yt[(i - 1) * 392 + 128 + c]); cnt += 1.f; }
      if (p >= 2) { s += bf2f(Yt[(i - 2) * 392 + 256 + c]); cnt += 1.f; }
      h = tanhf(fmaf(cnt, b1[c], s));
    }
    Yt[(i - 2) * 392 + 256 + c] = f2bf_r(h);          // = Yt[hl][256+c], holds H[r0-2+hl]
  }
  __syncthreads();

  // ---- stage-2: Z rows r0+wave*16..+15; A-frag H row = Yt[wave*16+mrow+j][256+...] ----
  f32x4 acc2[8] = {};
#pragma unroll
  for (int j = 0; j < 3; ++j) {
#pragma unroll
    for (int kk = 0; kk < 4; ++kk) {
      short8 a0 = *(const short8*)&Yt[(wave * 16 + mrow + j) * 392 + 256 + kk * 32 + quad * 8];
      const unsigned short* wp = W2t + (size_t)(j * 128 + mrow) * 128 + kk * 32 + quad * 8;
#pragma unroll
      for (int ct = 0; ct < 8; ++ct)
        acc2[ct] = MFMA16(a0, *(const short8*)(wp + ct * 16 * 128), acc2[ct]);
    }
  }

  // ---- log-softmax per row (128 cols = 16 lanes x 8 ct-regs) ----
#pragma unroll
  for (int rg = 0; rg < 4; ++rg) {
    float z[8]; float m = -1e30f;
#pragma unroll
    for (int ct = 0; ct < 8; ++ct) {
      z[ct] = acc2[ct][rg] + 3.f * b2[ct * 16 + mrow];
      m = fmaxf(m, z[ct]);
    }
#pragma unroll
    for (int off = 1; off < 16; off <<= 1) m = fmaxf(m, __shfl_xor(m, off, 64));
    float s = 0.f;
#pragma unroll
    for (int ct = 0; ct < 8; ++ct) s += __expf(z[ct] - m);
#pragma unroll
    for (int off = 1; off < 16; off <<= 1) s += __shfl_xor(s, off, 64);
    float lse = m + __logf(s);
    int grow = r0 + wave * 16 + quad * 4 + rg;
    if (grow >= 2) {
      float* op = out + (size_t)grow * 128 + mrow;
#pragma unroll
      for (int ct = 0; ct < 8; ++ct) op[ct * 16] = z[ct] - lse;
    }
  }

  // ---- fallback rows 0,1 (block 0): Z0 = tanh(Y[row][0:128]+b1) @ W2[0] + b2 ----
  if (blockIdx.x == 0) {
    __syncthreads();
    int row = tid >> 7, d = tid & 127;
    zbuf[row * 128 + d] = tanhf(bf2f(Yt[(row + 4) * 392 + d]) + b1[d]);  // blk0 cols intact
    __syncthreads();
    float zv = b2[d];
    for (int c = 0; c < 128; ++c)
      zv = fmaf(zbuf[row * 128 + c], bf2f(W2t[(size_t)d * 128 + c]), zv); // W2t[0][d][c]=W2[0][c][d]
    __syncthreads();
    zbuf[row * 128 + d] = zv;
    __syncthreads();
    float m = -1e30f;
    for (int c = 0; c < 128; ++c) m = fmaxf(m, zbuf[row * 128 + c]);
    float s = 0.f;
    for (int c = 0; c < 128; ++c) s += __expf(zbuf[row * 128 + c] - m);
    out[(size_t)row * 128 + d] = zv - m - __logf(s);
  }
}

// ---------- launch ----------
extern "C" void kernel_launch(void* const* d_in, const int* in_sizes, int n_in,
                              void* d_out, int out_size, void* d_ws, size_t ws_size,
                              hipStream_t stream) {
  const float* X  = (const float*)d_in[0];   // [32768, 1, 2048]
  const float* W1 = (const float*)d_in[1];   // [3, 2048, 128]
  const float* b1 = (const float*)d_in[2];   // [1, 128]
  const float* W2 = (const float*)d_in[3];   // [3, 128, 128]
  const float* b2 = (const float*)d_in[4];   // [1, 128]
  float* out = (float*)d_out;                // [32768, 1, 128] fp32

  unsigned short* W1bt = (unsigned short*)d_ws;                    // 384*2048*2 = 1,572,864
  unsigned short* W2t  = (unsigned short*)((char*)d_ws + 1572864); // 98,304

  k_repack<<<288, 256, 0, stream>>>(W1, W2, W1bt, W2t);
  k_fused<<<512, 256, 0, stream>>>(X, W1bt, W2t, b1, b2, out);
}

// Round 3
// 441.639 us; speedup vs baseline: 1.0233x; 1.0005x over previous
//
#include <hip/hip_runtime.h>
#include <math.h>

// ---------- types / helpers ----------
typedef __attribute__((ext_vector_type(8))) short short8;   // 8 bf16 (4 VGPRs)
typedef __attribute__((ext_vector_type(4))) float f32x4;    // MFMA acc

#define MFMA16(a, b, c) __builtin_amdgcn_mfma_f32_16x16x32_bf16((a), (b), (c), 0, 0, 0)

// async global->LDS, 16B per lane. LDS dest is wave-uniform base + lane*16;
// the GLOBAL source address is per-lane -> swizzle the source for free.
__device__ inline void gl_lds16(const void* g, void* l) {
  __builtin_amdgcn_global_load_lds(
      (const __attribute__((address_space(1))) void*)g,
      (__attribute__((address_space(3))) void*)l, 16, 0, 0);
}

__device__ inline unsigned int pack2(float lo, float hi) {
  unsigned int ulo = __float_as_uint(lo), uhi = __float_as_uint(hi);
  return (uhi & 0xFFFF0000u) | (ulo >> 16);
}
__device__ inline unsigned short f2bf_r(float f) {
  return (unsigned short)((__float_as_uint(f) + 0x8000u) >> 16);
}
__device__ inline float bf2f(unsigned short h) {
  return __uint_as_float(((unsigned int)h) << 16);
}

// ---------- K0: merged weight repack ----------
// blocks 0..95:   W1 [3,2048,128] f32 -> W1bt [384,2048] bf16 (B^T, k-contiguous)
// blocks 96..287: W2 [3,128,128] f32  -> W2t  [j][d][c]  bf16 (transposed)
__global__ __launch_bounds__(256) void k_repack(const float* __restrict__ W1,
                                                const float* __restrict__ W2,
                                                unsigned short* __restrict__ W1bt,
                                                unsigned short* __restrict__ W2t) {
  __shared__ float tile[64 * 128];   // 32 KB
  const int b = blockIdx.x, tid = threadIdx.x;
  if (b < 96) {
    const int k = b >> 5, et = b & 31;
    const int e0 = et * 64;
    const float* src = W1 + (size_t)k * 262144 + (size_t)e0 * 128;
#pragma unroll
    for (int i = 0; i < 8; ++i) {
      int idx4 = tid + i * 256;
      ((f32x4*)tile)[idx4] = ((const f32x4*)src)[idx4];
    }
    __syncthreads();
#pragma unroll
    for (int i = 0; i < 4; ++i) {
      int item = tid + i * 256;
      int c = item >> 3, eo = (item & 7) * 8;
      union { unsigned short h[8]; uint4 v; } t;
#pragma unroll
      for (int u = 0; u < 8; ++u) t.h[u] = f2bf_r(tile[(eo + u) * 128 + c]);
      *(uint4*)(W1bt + (size_t)(k * 128 + c) * 2048 + e0 + eo) = t.v;
    }
  } else {
    int idx = (b - 96) * 256 + tid;                 // 49152
    int j = idx >> 14, r = idx & 16383, d = r >> 7, c = r & 127;
    W2t[idx] = f2bf_r(W2[(size_t)j * 16384 + (size_t)c * 128 + d]);
  }
}

// ---------- K1: fused stage1 GEMM + tap-sum/tanh + stage2 GEMM + log-softmax ----------
// 256 blocks x 512 threads (8 waves = 2 row-groups x 4 col-groups), 128 out rows/block.
// Stage-1 logical rows r0-4..r0+131 (136 staged, 144 logical). BK=32, TRIPLE-buffered
// LDS (3 x 43008 B = 129 KB, 1 block/CU) with counted-vmcnt pipeline (T4): raw
// s_barrier + per-wave s_waitcnt vmcnt(S) -- stage loads stay in flight across the
// barrier; vmcnt never drains to 0 in the main loop (the m218 lever).
//
// Buffer layout (per 43008-B buffer):
//   A: chunk-plane-major, plane p (p=0..7, 16B = 4 floats of the 32-float K-chunk)
//      at +p*2304, row r (0..143, row i <-> X row r0-4+i) at +r*16.   (18432 B)
//      -> frag read banks: (p*144 + r) % 8 = r%8 -> 2-way within 16-lane group (free).
//   B: at +18432, col c (0..383) stride 64 B; 16B slot s holds k-chunk s^((c>>1)&3).
//      -> frag read groups: (4*(c&1) + q^((c>>1)&3))%8 bijective over 16 cols (2-way).
__global__ __launch_bounds__(512, 2) void k_fused(const float* __restrict__ X,
                                                  const unsigned short* __restrict__ Bt,
                                                  const unsigned short* __restrict__ W2t,
                                                  const float* __restrict__ b1,
                                                  const float* __restrict__ b2,
                                                  float* __restrict__ out) {
  constexpr int BUF = 43008, BOFF = 18432;
  __shared__ __align__(16) char smem[3 * 43008];          // 129,024 B
  unsigned short* Yt = (unsigned short*)smem;             // phase B: 136 x 392 bf16 (106,624 B)
  float* zbuf = (float*)(smem + 106624);                  // 2 x 128 f32

  const int r0 = blockIdx.x * 128;
  const int tid = threadIdx.x, wave = tid >> 6, lane = tid & 63;
  const int mrow = lane & 15, quad = lane >> 4;
  const int wr = wave >> 2, wc = wave & 3;                // row-group / col-group

  // ---- A staging: 18 loads (1152 units of 16B; unit u: plane u/144, row u%144).
  // wave w owns loads {w, w+8}; waves 0,1 also own {16,17}.
  const float* agp[3];
  {
    const int Ls[3] = { wave, wave + 8, 16 + wave };
#pragma unroll
    for (int jj = 0; jj < 3; ++jj) {
      int u = Ls[jj] * 64 + lane;
      int pl = u / 144, rr = u - pl * 144;
      if (pl > 7) pl = 7;                               // waves>=2 jj==2: never issued
      int g = r0 - 4 + rr;
      if (g < 0) g = 0;
      if (g > 32767) g = 32767;                         // halo clamps (masked later)
      agp[jj] = X + (size_t)g * 2048 + pl * 4;
    }
  }
  // ---- B staging: 24 loads (16 cols each), wave w owns loads w*3..w*3+2.
  // dest unit = lane: col = bcol + (lane>>2), slot = lane&3 -> k-chunk (lane&3)^((lane>>3)&3).
  const unsigned short* bgp[3];
#pragma unroll
  for (int jj = 0; jj < 3; ++jj) {
    int col = (wave * 3 + jj) * 16 + (lane >> 2);
    int kc = (lane & 3) ^ ((lane >> 3) & 3);
    bgp[jj] = Bt + (size_t)col * 2048 + kc * 8;
  }

  f32x4 acc[5][6] = {};   // wave: rows wr*80 + rt*16.. (wr1 rt4 = rows 144.. garbage, unused)

  auto stage = [&](char* base) {
    gl_lds16(agp[0], base + wave * 1024);
    gl_lds16(agp[1], base + (wave + 8) * 1024);
    if (wave < 2) gl_lds16(agp[2], base + (16 + wave) * 1024);
#pragma unroll
    for (int jj = 0; jj < 3; ++jj)
      gl_lds16(bgp[jj], base + BOFF + (wave * 3 + jj) * 1024);
#pragma unroll
    for (int jj = 0; jj < 3; ++jj) agp[jj] += 32;       // next K-chunk
#pragma unroll
    for (int jj = 0; jj < 3; ++jj) bgp[jj] += 32;
  };

  auto compute = [&](const char* base) {
    const char* Ab = base;
    const unsigned short* Bb = (const unsigned short*)(base + BOFF);
    short8 af[5];
#pragma unroll
    for (int rt = 0; rt < 5; ++rt) {
      int row = wr * 80 + rt * 16 + mrow;
      f32x4 x0 = *(const f32x4*)(Ab + (quad * 2) * 2304 + row * 16);
      f32x4 x1 = *(const f32x4*)(Ab + (quad * 2 + 1) * 2304 + row * 16);
      union { unsigned int u[4]; short8 v; } tt;
      tt.u[0] = pack2(x0[0], x0[1]); tt.u[1] = pack2(x0[2], x0[3]);
      tt.u[2] = pack2(x1[0], x1[1]); tt.u[3] = pack2(x1[2], x1[3]);
      af[rt] = tt.v;
    }
#pragma unroll
    for (int ct = 0; ct < 6; ++ct) {
      int col = wc * 96 + ct * 16 + mrow;
      int slot = quad ^ ((mrow >> 1) & 3);
      short8 bf = *(const short8*)(Bb + col * 32 + slot * 8);
#pragma unroll
      for (int rt = 0; rt < 5; ++rt)
        acc[rt][ct] = MFMA16(af[rt], bf, acc[rt][ct]);
    }
  };

  // ---- prologue: chunks 0,1 in flight (2S outstanding per wave) ----
  stage(smem);
  stage(smem + BUF);

  int cur = 0, nx2 = 2;
  for (int t = 0; t < 63; ++t) {
    // wait own stage(t) loads (leave stage(t+1) in flight), then sync all waves
    if (wave < 2) asm volatile("s_waitcnt vmcnt(6)" ::: "memory");
    else          asm volatile("s_waitcnt vmcnt(5)" ::: "memory");
    __builtin_amdgcn_s_barrier();
    __builtin_amdgcn_sched_barrier(0);
    if (t < 62) stage(smem + nx2 * BUF);   // safe: all waves done compute(t-1)
    compute(smem + cur * BUF);
    cur = (cur == 2) ? 0 : cur + 1;
    nx2 = (nx2 == 2) ? 0 : nx2 + 1;
  }
  asm volatile("s_waitcnt vmcnt(0)" ::: "memory");
  __builtin_amdgcn_s_barrier();
  __builtin_amdgcn_sched_barrier(0);
  compute(smem + cur * BUF);               // chunk 63
  __syncthreads();                          // buffers die; Yt phase begins

  // ---- spill acc -> Yt (bf16). Yt row i <-> Y global row r0-4+i; stride 392 ----
#pragma unroll
  for (int rt = 0; rt < 5; ++rt)
#pragma unroll
    for (int ct = 0; ct < 6; ++ct)
#pragma unroll
      for (int rg = 0; rg < 4; ++rg) {
        int l = wr * 80 + rt * 16 + quad * 4 + rg;
        int col = wc * 96 + ct * 16 + mrow;
        if (l < 136) Yt[l * 392 + col] = f2bf_r(acc[rt][ct][rg]);
      }
  __syncthreads();

  // ---- H[p]=tanh(sum taps + cnt*b1), p in [r0-2, r0+127]; store at dead tap-2 slot ----
  // H[p] slot = Yt[p-r0+2][256+c]. Self-RMW per element: race-free.
  for (int idx = tid; idx < 130 * 128; idx += 512) {
    int hl = idx >> 7, c = idx & 127;
    int p = r0 - 2 + hl;
    int i = hl + 2;                                   // tap-0 Yt row
    float h = 0.f;
    if (p >= 0) {
      float s = bf2f(Yt[i * 392 + c]);
      float cnt = 1.f;
      if (p >= 1) { s += bf2f(Yt[(i - 1) * 392 + 128 + c]); cnt += 1.f; }
      if (p >= 2) { s += bf2f(Yt[(i - 2) * 392 + 256 + c]); cnt += 1.f; }
      h = tanhf(fmaf(cnt, b1[c], s));
    }
    Yt[(i - 2) * 392 + 256 + c] = f2bf_r(h);          // = Yt[hl][256+c], holds H[r0-2+hl]
  }
  __syncthreads();

  // ---- stage-2: Z rows r0+wave*16..+15; A-frag H row = Yt[wave*16+mrow+j][256+...] ----
  f32x4 acc2[8] = {};
#pragma unroll
  for (int j = 0; j < 3; ++j) {
#pragma unroll
    for (int kk = 0; kk < 4; ++kk) {
      short8 a0 = *(const short8*)&Yt[(wave * 16 + mrow + j) * 392 + 256 + kk * 32 + quad * 8];
      const unsigned short* wp = W2t + (size_t)(j * 128 + mrow) * 128 + kk * 32 + quad * 8;
#pragma unroll
      for (int ct = 0; ct < 8; ++ct)
        acc2[ct] = MFMA16(a0, *(const short8*)(wp + ct * 16 * 128), acc2[ct]);
    }
  }

  // ---- log-softmax per row (128 cols = 16 lanes x 8 ct-regs) ----
#pragma unroll
  for (int rg = 0; rg < 4; ++rg) {
    float z[8]; float m = -1e30f;
#pragma unroll
    for (int ct = 0; ct < 8; ++ct) {
      z[ct] = acc2[ct][rg] + 3.f * b2[ct * 16 + mrow];
      m = fmaxf(m, z[ct]);
    }
#pragma unroll
    for (int off = 1; off < 16; off <<= 1) m = fmaxf(m, __shfl_xor(m, off, 64));
    float s = 0.f;
#pragma unroll
    for (int ct = 0; ct < 8; ++ct) s += __expf(z[ct] - m);
#pragma unroll
    for (int off = 1; off < 16; off <<= 1) s += __shfl_xor(s, off, 64);
    float lse = m + __logf(s);
    int grow = r0 + wave * 16 + quad * 4 + rg;
    if (grow >= 2) {
      float* op = out + (size_t)grow * 128 + mrow;
#pragma unroll
      for (int ct = 0; ct < 8; ++ct) op[ct * 16] = z[ct] - lse;
    }
  }

  // ---- fallback rows 0,1 (block 0): Z0 = tanh(Y[row][0:128]+b1) @ W2[0] + b2 ----
  if (blockIdx.x == 0) {
    __syncthreads();
    int row = tid >> 7, d = tid & 127;
    if (tid < 256)
      zbuf[row * 128 + d] = tanhf(bf2f(Yt[(row + 4) * 392 + d]) + b1[d]); // tap0 cols intact
    __syncthreads();
    float zv = 0.f;
    if (tid < 256) {
      zv = b2[d];
      for (int c = 0; c < 128; ++c)
        zv = fmaf(zbuf[row * 128 + c], bf2f(W2t[(size_t)d * 128 + c]), zv); // W2t[0][d][c]
    }
    __syncthreads();
    if (tid < 256) zbuf[row * 128 + d] = zv;
    __syncthreads();
    if (tid < 256) {
      float m = -1e30f;
      for (int c = 0; c < 128; ++c) m = fmaxf(m, zbuf[row * 128 + c]);
      float s = 0.f;
      for (int c = 0; c < 128; ++c) s += __expf(zbuf[row * 128 + c] - m);
      out[(size_t)row * 128 + d] = zv - m - __logf(s);
    }
  }
}

// ---------- launch ----------
extern "C" void kernel_launch(void* const* d_in, const int* in_sizes, int n_in,
                              void* d_out, int out_size, void* d_ws, size_t ws_size,
                              hipStream_t stream) {
  const float* X  = (const float*)d_in[0];   // [32768, 1, 2048]
  const float* W1 = (const float*)d_in[1];   // [3, 2048, 128]
  const float* b1 = (const float*)d_in[2];   // [1, 128]
  const float* W2 = (const float*)d_in[3];   // [3, 128, 128]
  const float* b2 = (const float*)d_in[4];   // [1, 128]
  float* out = (float*)d_out;                // [32768, 1, 128] fp32

  unsigned short* W1bt = (unsigned short*)d_ws;                    // 384*2048*2 = 1,572,864
  unsigned short* W2t  = (unsigned short*)((char*)d_ws + 1572864); // 98,304

  k_repack<<<288, 256, 0, stream>>>(W1, W2, W1bt, W2t);
  k_fused<<<256, 512, 0, stream>>>(X, W1bt, W2t, b1, b2, out);
}